// Round 1
// baseline (1604.653 us; speedup 1.0000x reference)
//
#include <hip/hip_runtime.h>

// Problem constants (VectorQuantizer: inputs [V,N,D] fp32, embeddings [V,D,K] fp32)
#define NV 16
#define NN 8192
#define ND 256
#define NK 1024

// GEMM tiling for score+argmin kernel
constexpr int TM = 128;   // rows (n) per block
constexpr int TC = 128;   // codes (k) per block-chunk
constexpr int DC = 32;    // depth chunk staged in LDS
constexpr int SX = 34;    // padded LDS stride for X rows (34*8 % 32 == 16 -> 2-way max on A reads)

// ---------------------------------------------------------------------------
// w_sq[v,k] = sum_d W[v,d,k]^2 in double; also zero the loss accumulator.
// ---------------------------------------------------------------------------
__global__ void wsq_kernel(const float* __restrict__ W, double* __restrict__ wsq,
                           double* __restrict__ acc) {
    int gid = blockIdx.x * 256 + threadIdx.x;       // V*K = 16384 threads
    int v = gid >> 10, k = gid & 1023;
    const float* Wv = W + (size_t)v * ND * NK + k;
    double s = 0.0;
    for (int d = 0; d < ND; ++d) {                  // lanes: consecutive k -> coalesced
        float w = Wv[(size_t)d * NK];
        s += (double)w * (double)w;
    }
    wsq[gid] = s;
    if (gid == 0) *acc = 0.0;                       // runs before gather_loss on the stream
}

// ---------------------------------------------------------------------------
// Transpose codebook: W [V,D,K] -> Wt [V,K,D] so the gather is coalesced.
// ---------------------------------------------------------------------------
__global__ void transpose_kernel(const float* __restrict__ W, float* __restrict__ Wt) {
    __shared__ float tile[32][33];
    int v = blockIdx.z;
    int k0 = blockIdx.x * 32, d0 = blockIdx.y * 32;
    int tx = threadIdx.x, ty = threadIdx.y;         // block (32,8)
    const float* Wv = W + (size_t)v * ND * NK;
    #pragma unroll
    for (int i = 0; i < 4; ++i)
        tile[ty + 8 * i][tx] = Wv[(size_t)(d0 + ty + 8 * i) * NK + k0 + tx];
    __syncthreads();
    float* Wtv = Wt + (size_t)v * NK * ND;
    #pragma unroll
    for (int i = 0; i < 4; ++i)
        Wtv[(size_t)(k0 + ty + 8 * i) * ND + d0 + tx] = tile[tx][ty + 8 * i];
}

// ---------------------------------------------------------------------------
// Fused fp32 SGEMM (X.W) + running argmin over s = ||w||^2 - 2 x.w.
// 128x128 tile, 8x8 micro-tile, Dc=32 LDS chunks. Argmin compare in double,
// tie -> smaller index (matches jnp.argmin first-min).
// ---------------------------------------------------------------------------
__global__ __launch_bounds__(256, 4) void score_argmin(
    const float* __restrict__ X, const float* __restrict__ W,
    const double* __restrict__ wsq, int* __restrict__ idx) {
    __shared__ float Xs[TM * SX];                    // [r][d], padded stride 34
    __shared__ __align__(16) float Ws[DC * TC];      // [d][c]

    const int tid = threadIdx.x;
    const int tx = tid & 15, ty = tid >> 4;
    const int v = blockIdx.x >> 6;                   // 64 blocks per v (8192/128)
    const int n0 = (blockIdx.x & 63) * TM;
    const float* Xb = X + ((size_t)v * NN + n0) * ND;
    const float* Wb = W + (size_t)v * ND * NK;
    const double* wsqv = wsq + v * NK;

    double bs[8];
    int bc[8];
    #pragma unroll
    for (int i = 0; i < 8; ++i) { bs[i] = 1e300; bc[i] = 0; }

    for (int cc = 0; cc < NK / TC; ++cc) {
        float p[8][8];
        #pragma unroll
        for (int i = 0; i < 8; ++i)
            #pragma unroll
            for (int j = 0; j < 8; ++j) p[i][j] = 0.f;

        for (int dc = 0; dc < ND / DC; ++dc) {
            const int d0 = dc * DC;
            // stage X chunk: 128 rows x 32 d, float2 per thread x 8 passes
            {
                const int dl2 = (tid & 15) * 2;
                const int rb = tid >> 4;
                #pragma unroll
                for (int ps = 0; ps < 8; ++ps) {
                    int r = ps * 16 + rb;
                    float2 val = *(const float2*)(Xb + (size_t)r * ND + d0 + dl2);
                    *(float2*)(&Xs[r * SX + dl2]) = val;
                }
            }
            // stage W chunk: 32 d x 128 c, float4 per thread x 4 passes
            {
                const int c4 = (tid & 31) * 4;
                const int db = tid >> 5;
                #pragma unroll
                for (int ps = 0; ps < 4; ++ps) {
                    int dl = ps * 8 + db;
                    float4 val = *(const float4*)(Wb + (size_t)(d0 + dl) * NK + cc * TC + c4);
                    *(float4*)(&Ws[dl * TC + c4]) = val;
                }
            }
            __syncthreads();
            #pragma unroll 4
            for (int dl = 0; dl < DC; ++dl) {
                float a[8];
                #pragma unroll
                for (int i = 0; i < 8; ++i) a[i] = Xs[(ty * 8 + i) * SX + dl];
                // cols split {4tx..4tx+3} and {64+4tx..} -> conflict-free b128 reads
                float4 b0 = *(const float4*)(&Ws[dl * TC + tx * 4]);
                float4 b1 = *(const float4*)(&Ws[dl * TC + 64 + tx * 4]);
                #pragma unroll
                for (int i = 0; i < 8; ++i) {
                    p[i][0] = fmaf(a[i], b0.x, p[i][0]);
                    p[i][1] = fmaf(a[i], b0.y, p[i][1]);
                    p[i][2] = fmaf(a[i], b0.z, p[i][2]);
                    p[i][3] = fmaf(a[i], b0.w, p[i][3]);
                    p[i][4] = fmaf(a[i], b1.x, p[i][4]);
                    p[i][5] = fmaf(a[i], b1.y, p[i][5]);
                    p[i][6] = fmaf(a[i], b1.z, p[i][6]);
                    p[i][7] = fmaf(a[i], b1.w, p[i][7]);
                }
            }
            __syncthreads();
        }
        // epilogue: fold this chunk's 8x8 scores into per-row best
        #pragma unroll
        for (int j = 0; j < 8; ++j) {
            int cl = (j < 4) ? (tx * 4 + j) : (64 + tx * 4 + (j - 4));
            int c = cc * TC + cl;
            double w2 = wsqv[c];
            #pragma unroll
            for (int i = 0; i < 8; ++i) {
                double s = w2 - 2.0 * (double)p[i][j];
                if (s < bs[i] || (s == bs[i] && c < bc[i])) { bs[i] = s; bc[i] = c; }
            }
        }
    }
    // cross-thread reduce over tx (16-lane groups within a wave), tie -> min c
    #pragma unroll
    for (int i = 0; i < 8; ++i) {
        double s = bs[i];
        int c = bc[i];
        #pragma unroll
        for (int m = 1; m < 16; m <<= 1) {
            double s2 = __shfl_xor(s, m, 64);
            int c2 = __shfl_xor(c, m, 64);
            if (s2 < s || (s2 == s && c2 < c)) { s = s2; c = c2; }
        }
        if (tx == 0) idx[v * NN + n0 + ty * 8 + i] = c;
    }
}

// ---------------------------------------------------------------------------
// Gather quantized rows, write output = x + (q - x), accumulate sum (q-x)^2.
// One block = 8 rows; float4 coalesced; one fp64 atomicAdd per block.
// ---------------------------------------------------------------------------
__global__ void gather_loss(const float* __restrict__ X, const float* __restrict__ Wt,
                            const int* __restrict__ idx, float* __restrict__ out,
                            double* __restrict__ acc) {
    int tid = threadIdx.x;
    float lsum = 0.f;
    #pragma unroll
    for (int i = 0; i < 2; ++i) {
        int flat = i * 256 + tid;                    // 0..511, one wave = one row
        int rl = flat >> 6;
        int dpos = (flat & 63) * 4;
        size_t row = (size_t)blockIdx.x * 8 + rl;
        int k = idx[row];                            // wave-uniform -> scalar load
        int v = (int)(row >> 13);                    // row / 8192
        float4 q = *(const float4*)(Wt + ((size_t)v * NK + k) * ND + dpos);
        float4 x = *(const float4*)(X + row * ND + dpos);
        float dx0 = q.x - x.x, dx1 = q.y - x.y, dx2 = q.z - x.z, dx3 = q.w - x.w;
        float4 o;                                    // emulate x + (q - x) exactly
        o.x = x.x + dx0; o.y = x.y + dx1; o.z = x.z + dx2; o.w = x.w + dx3;
        *(float4*)(out + row * ND + dpos) = o;
        lsum += dx0 * dx0 + dx1 * dx1 + dx2 * dx2 + dx3 * dx3;
    }
    #pragma unroll
    for (int m = 32; m >= 1; m >>= 1) lsum += __shfl_down(lsum, m, 64);
    __shared__ float ws4[4];
    if ((tid & 63) == 0) ws4[tid >> 6] = lsum;
    __syncthreads();
    if (tid == 0) {
        float tot = ws4[0] + ws4[1] + ws4[2] + ws4[3];
        atomicAdd(acc, (double)tot);
    }
}

__global__ void finalize_loss(const double* __restrict__ acc, float* __restrict__ outLoss) {
    *outLoss = (float)(1.25 * (*acc) / (double)((size_t)NV * NN * ND));
}

// ---------------------------------------------------------------------------
extern "C" void kernel_launch(void* const* d_in, const int* in_sizes, int n_in,
                              void* d_out, int out_size, void* d_ws, size_t ws_size,
                              hipStream_t stream) {
    const float* X = (const float*)d_in[0];   // [16, 8192, 256]
    const float* W = (const float*)d_in[1];   // [16, 256, 1024]
    float* out = (float*)d_out;               // [16,8192,256] + loss scalar

    char* ws = (char*)d_ws;
    float* Wt    = (float*)ws;                                 // 16 MB
    double* wsq  = (double*)(ws + 16777216);                   // 128 KB
    int* idx     = (int*)(ws + 16777216 + 131072);             // 512 KB
    double* acc  = (double*)(ws + 16777216 + 131072 + 524288); // 8 B

    wsq_kernel<<<64, 256, 0, stream>>>(W, wsq, acc);
    transpose_kernel<<<dim3(NK / 32, ND / 32, NV), dim3(32, 8), 0, stream>>>(W, Wt);
    score_argmin<<<(NV * NN) / TM, 256, 0, stream>>>(X, W, wsq, idx);
    gather_loss<<<(NV * NN) / 8, 256, 0, stream>>>(X, Wt, idx, out, acc);
    finalize_loss<<<1, 1, 0, stream>>>(acc, out + (size_t)NV * NN * ND);
}

// Round 2
// 770.109 us; speedup vs baseline: 2.0837x; 2.0837x over previous
//
#include <hip/hip_runtime.h>

// Problem constants (VectorQuantizer: inputs [V,N,D] fp32, embeddings [V,D,K] fp32)
#define NV 16
#define NN 8192
#define ND 256
#define NK 1024

typedef __attribute__((ext_vector_type(8))) short short8;
typedef __attribute__((ext_vector_type(4))) float f32x4;

// bf16 helpers (RNE), deterministic and header-independent
__device__ __forceinline__ ushort f2bf(float f) {
    uint32_t u = __float_as_uint(f);
    uint32_t r = (u + 0x7FFFu + ((u >> 16) & 1u)) >> 16;
    return (ushort)r;
}
__device__ __forceinline__ float bf2f(ushort h) {
    return __uint_as_float(((uint32_t)h) << 16);
}

// ===========================================================================
// MFMA-path kernels
// ===========================================================================

// wsq (double + float) and zero the loss/count accumulators.
__global__ void wsq_prep(const float* __restrict__ W, double* __restrict__ wsqd,
                         float* __restrict__ wsqf, double* __restrict__ acc,
                         int* __restrict__ count) {
    int gid = blockIdx.x * 256 + threadIdx.x;       // V*K threads
    int v = gid >> 10, k = gid & 1023;
    const float* Wv = W + (size_t)v * ND * NK + k;
    double s = 0.0;
    for (int d = 0; d < ND; ++d) {
        float w = Wv[(size_t)d * NK];
        s += (double)w * (double)w;
    }
    wsqd[gid] = s;
    wsqf[gid] = (float)s;
    if (gid == 0) { *acc = 0.0; *count = 0; }
}

// Transpose W [V,D,K] -> Wt [V,K,D] fp32 (for gather) + bf16 limb copies.
__global__ void prep_w(const float* __restrict__ W, float* __restrict__ Wt,
                       ushort* __restrict__ Wht, ushort* __restrict__ Wlt) {
    __shared__ float tile[32][33];
    int v = blockIdx.z;
    int k0 = blockIdx.x * 32, d0 = blockIdx.y * 32;
    int tx = threadIdx.x, ty = threadIdx.y;         // block (32,8)
    const float* Wv = W + (size_t)v * ND * NK;
    #pragma unroll
    for (int i = 0; i < 4; ++i)
        tile[ty + 8 * i][tx] = Wv[(size_t)(d0 + ty + 8 * i) * NK + k0 + tx];
    __syncthreads();
    size_t ob = (size_t)v * NK * ND;
    #pragma unroll
    for (int i = 0; i < 4; ++i) {
        float val = tile[tx][ty + 8 * i];
        size_t o = ob + (size_t)(k0 + ty + 8 * i) * ND + d0 + tx;
        Wt[o] = val;
        ushort h = f2bf(val);
        Wht[o] = h;
        Wlt[o] = f2bf(val - bf2f(h));
    }
}

// X [V,N,D] fp32 -> Xh, Xl bf16 limb arrays.
__global__ void prep_x(const float* __restrict__ X, ushort* __restrict__ Xh,
                       ushort* __restrict__ Xl) {
    const int nth = gridDim.x * 256;
    for (size_t g = (size_t)blockIdx.x * 256 + threadIdx.x; g < (size_t)NV * NN * ND / 4;
         g += nth) {
        float4 x = *(const float4*)(X + g * 4);
        ushort4 h, l;
        h.x = f2bf(x.x); l.x = f2bf(x.x - bf2f(h.x));
        h.y = f2bf(x.y); l.y = f2bf(x.y - bf2f(h.y));
        h.z = f2bf(x.z); l.z = f2bf(x.z - bf2f(h.z));
        h.w = f2bf(x.w); l.w = f2bf(x.w - bf2f(h.w));
        *(ushort4*)(Xh + g * 4) = h;
        *(ushort4*)(Xl + g * 4) = l;
    }
}

// ---------------------------------------------------------------------------
// MFMA score kernel: 128 rows/block, loop over 8 col-chunks of 128.
// 2-limb bf16: dot = Xh.Wh + Xh.Wl + Xl.Wh (3 chained mfma_f32_16x16x32_bf16).
// Tracks per-row best (s1,c1) AND second-best s2 -> margin for rescue pass.
// m97-style staging: global_load_lds width 16, LDS [row][32d] bf16 rows.
// ---------------------------------------------------------------------------
__global__ __launch_bounds__(256, 2) void score_mfma(
    const ushort* __restrict__ Xh, const ushort* __restrict__ Xl,
    const ushort* __restrict__ Wht, const ushort* __restrict__ Wlt,
    const float* __restrict__ wsqf, int* __restrict__ idx, float* __restrict__ marg) {
    // LDS: A region [0,16384): seg*16, hi limb segs 0..511 ([row][q]), lo 512..1023
    //      B region [16384,32768): same over cols
    //      merge region [32768, 35840)
    __shared__ __align__(16) unsigned char smem[35840];

    const int tid = threadIdx.x;
    const int w = tid >> 6;                          // wave 0..3
    const int l15 = tid & 15;
    const int l4 = (tid >> 4) & 3;                   // lane quad within wave
    const int v = blockIdx.x >> 6;
    const int n0 = (blockIdx.x & 63) * 128;
    const int rowq = (w & 1) * 64;                   // wave row base in tile
    const int colq = (w >> 1) * 64;                  // wave col base in chunk

    const ushort* Abase0 = Xh + (size_t)(v * NN + n0) * ND;
    const ushort* Abase1 = Xl + (size_t)(v * NN + n0) * ND;
    const ushort* Bbase0 = Wht + (size_t)v * NK * ND;
    const ushort* Bbase1 = Wlt + (size_t)v * NK * ND;

    float m1[16], m2[16];
    int c1[16];
    #pragma unroll
    for (int s = 0; s < 16; ++s) { m1[s] = 3.0e38f; m2[s] = 3.0e38f; c1[s] = 0; }

    for (int cc = 0; cc < 8; ++cc) {
        f32x4 acc[4][4];
        #pragma unroll
        for (int i = 0; i < 4; ++i)
            #pragma unroll
            for (int j = 0; j < 4; ++j) acc[i][j] = (f32x4){0.f, 0.f, 0.f, 0.f};

        for (int dc = 0; dc < 8; ++dc) {
            const int d0 = dc * 32;
            #pragma unroll
            for (int i = 0; i < 4; ++i) {            // A: 1024 segs of 16B
                int seg = i * 256 + tid;
                int s2i = seg & 511;
                int row = s2i >> 2, q = s2i & 3;
                const ushort* g = ((seg >> 9) ? Abase1 : Abase0) + (size_t)row * ND + d0 + q * 8;
                __builtin_amdgcn_global_load_lds(
                    (const __attribute__((address_space(1))) void*)g,
                    (__attribute__((address_space(3))) void*)(smem + seg * 16), 16, 0, 0);
            }
            #pragma unroll
            for (int i = 0; i < 4; ++i) {            // B: 1024 segs of 16B
                int seg = i * 256 + tid;
                int s2i = seg & 511;
                int col = s2i >> 2, q = s2i & 3;
                const ushort* g = ((seg >> 9) ? Bbase1 : Bbase0) +
                                  (size_t)(cc * 128 + col) * ND + d0 + q * 8;
                __builtin_amdgcn_global_load_lds(
                    (const __attribute__((address_space(1))) void*)g,
                    (__attribute__((address_space(3))) void*)(smem + 16384 + seg * 16), 16, 0, 0);
            }
            __syncthreads();
            short8 Ah[4], Al[4], Bh[4], Bl[4];
            #pragma unroll
            for (int rt = 0; rt < 4; ++rt) {
                int off = (rowq + rt * 16 + l15) * 64 + l4 * 16;
                Ah[rt] = *(const short8*)(smem + off);
                Al[rt] = *(const short8*)(smem + 8192 + off);
            }
            #pragma unroll
            for (int ct = 0; ct < 4; ++ct) {
                int off = 16384 + (colq + ct * 16 + l15) * 64 + l4 * 16;
                Bh[ct] = *(const short8*)(smem + off);
                Bl[ct] = *(const short8*)(smem + 8192 + off);
            }
            #pragma unroll
            for (int rt = 0; rt < 4; ++rt)
                #pragma unroll
                for (int ct = 0; ct < 4; ++ct) {
                    acc[rt][ct] = __builtin_amdgcn_mfma_f32_16x16x32_bf16(
                        Ah[rt], Bh[ct], acc[rt][ct], 0, 0, 0);
                    acc[rt][ct] = __builtin_amdgcn_mfma_f32_16x16x32_bf16(
                        Ah[rt], Bl[ct], acc[rt][ct], 0, 0, 0);
                    acc[rt][ct] = __builtin_amdgcn_mfma_f32_16x16x32_bf16(
                        Al[rt], Bh[ct], acc[rt][ct], 0, 0, 0);
                }
            __syncthreads();
        }
        // fold this chunk into running per-row best/second (lane-local slots)
        float wf[4];
        #pragma unroll
        for (int ct = 0; ct < 4; ++ct)
            wf[ct] = wsqf[v * NK + cc * 128 + colq + ct * 16 + l15];
        #pragma unroll
        for (int rt = 0; rt < 4; ++rt)
            #pragma unroll
            for (int reg = 0; reg < 4; ++reg) {
                int slot = rt * 4 + reg;
                #pragma unroll
                for (int ct = 0; ct < 4; ++ct) {
                    float s = fmaf(-2.0f, acc[rt][ct][reg], wf[ct]);
                    int c = cc * 128 + colq + ct * 16 + l15;
                    bool better = s < m1[slot];      // lane stream has ascending c
                    m2[slot] = better ? m1[slot] : fminf(m2[slot], s);
                    c1[slot] = better ? c : c1[slot];
                    m1[slot] = better ? s : m1[slot];
                }
            }
    }
    // merge across the 16 lanes sharing each row (C layout: col = lane&15)
    float* mS = (float*)(smem + 32768);              // [2][128]
    int* mC = (int*)(smem + 32768 + 1024);
    float* mS2 = (float*)(smem + 32768 + 2048);
    #pragma unroll
    for (int rt = 0; rt < 4; ++rt)
        #pragma unroll
        for (int reg = 0; reg < 4; ++reg) {
            int slot = rt * 4 + reg;
            float s1 = m1[slot], s2v = m2[slot];
            int c = c1[slot];
            #pragma unroll
            for (int m = 1; m < 16; m <<= 1) {
                float s1o = __shfl_xor(s1, m, 64);
                float s2o = __shfl_xor(s2v, m, 64);
                int co = __shfl_xor(c, m, 64);
                bool take = (s1o < s1) || (s1o == s1 && co < c);  // tie -> smaller c
                float big = take ? s1 : s1o;
                s2v = fminf(fminf(s2v, s2o), big);
                s1 = take ? s1o : s1;
                c = take ? co : c;
            }
            if (l15 == 0) {
                int rowl = rowq + rt * 16 + l4 * 4 + reg;   // C row = quad*4+reg
                int ch = w >> 1;
                mS[ch * 128 + rowl] = s1;
                mC[ch * 128 + rowl] = c;
                mS2[ch * 128 + rowl] = s2v;
            }
        }
    __syncthreads();
    if (tid < 128) {                                  // merge the two col-halves
        float s1a = mS[tid], s1b = mS[128 + tid];
        int ca = mC[tid], cb = mC[128 + tid];
        float s2a = mS2[tid], s2b = mS2[128 + tid];
        bool take = (s1b < s1a) || (s1b == s1a && cb < ca);
        float s1 = take ? s1b : s1a;
        int c = take ? cb : ca;
        float s2v = fminf(fminf(s2a, s2b), take ? s1a : s1b);
        idx[v * NN + n0 + tid] = c;
        marg[v * NN + n0 + tid] = s2v - s1;
    }
}

// Rows with small margin -> compacted list for exact rescoring.
__global__ void compact(const float* __restrict__ marg, int* __restrict__ list,
                        int* __restrict__ count) {
    int r = blockIdx.x * 256 + threadIdx.x;
    if (marg[r] < 0.04f) {
        int p = atomicAdd(count, 1);
        list[p] = r;
    }
}

// Exact fp32 rescore (same arithmetic class as the round-1 passing kernel:
// sequential fmaf over d ascending, double compare, tie -> smaller c).
__global__ __launch_bounds__(256) void rescore(
    const float* __restrict__ X, const float* __restrict__ W,
    const double* __restrict__ wsqd, const int* __restrict__ list,
    const int* __restrict__ count, int* __restrict__ idx) {
    __shared__ float xs[256];
    __shared__ double rs[4];
    __shared__ int rc[4];
    int tid = threadIdx.x;
    int nrows = *count;
    for (int j = blockIdx.x; j < nrows; j += gridDim.x) {
        int row = list[j];
        int v = row >> 13;
        __syncthreads();
        xs[tid] = X[(size_t)row * ND + tid];
        __syncthreads();
        const float* Wv = W + (size_t)v * ND * NK;
        float p0 = 0.f, p1 = 0.f, p2 = 0.f, p3 = 0.f;
        int cb = tid * 4;
        for (int d = 0; d < ND; ++d) {
            float xd = xs[d];
            float4 wv = *(const float4*)(Wv + (size_t)d * NK + cb);
            p0 = fmaf(xd, wv.x, p0);
            p1 = fmaf(xd, wv.y, p1);
            p2 = fmaf(xd, wv.z, p2);
            p3 = fmaf(xd, wv.w, p3);
        }
        const double* wv2 = wsqd + v * NK;
        double s0 = wv2[cb] - 2.0 * (double)p0;
        double s1 = wv2[cb + 1] - 2.0 * (double)p1;
        double s2 = wv2[cb + 2] - 2.0 * (double)p2;
        double s3 = wv2[cb + 3] - 2.0 * (double)p3;
        double bsv = s0;
        int bcv = cb;
        if (s1 < bsv) { bsv = s1; bcv = cb + 1; }
        if (s2 < bsv) { bsv = s2; bcv = cb + 2; }
        if (s3 < bsv) { bsv = s3; bcv = cb + 3; }
        for (int m = 1; m < 64; m <<= 1) {
            double so = __shfl_xor(bsv, m, 64);
            int co = __shfl_xor(bcv, m, 64);
            if (so < bsv || (so == bsv && co < bcv)) { bsv = so; bcv = co; }
        }
        if ((tid & 63) == 0) { rs[tid >> 6] = bsv; rc[tid >> 6] = bcv; }
        __syncthreads();
        if (tid == 0) {
            double b = rs[0];
            int c = rc[0];
            for (int i2 = 1; i2 < 4; ++i2)
                if (rs[i2] < b || (rs[i2] == b && rc[i2] < c)) { b = rs[i2]; c = rc[i2]; }
            idx[row] = c;
        }
        __syncthreads();
    }
}

// ===========================================================================
// Round-1 fallback kernels (known-passing fp32 path) — used if ws too small.
// ===========================================================================
constexpr int TM = 128;
constexpr int TC = 128;
constexpr int DC = 32;
constexpr int SX = 34;

__global__ void wsq_kernel(const float* __restrict__ W, double* __restrict__ wsq,
                           double* __restrict__ acc) {
    int gid = blockIdx.x * 256 + threadIdx.x;
    int v = gid >> 10, k = gid & 1023;
    const float* Wv = W + (size_t)v * ND * NK + k;
    double s = 0.0;
    for (int d = 0; d < ND; ++d) {
        float w = Wv[(size_t)d * NK];
        s += (double)w * (double)w;
    }
    wsq[gid] = s;
    if (gid == 0) *acc = 0.0;
}

__global__ void transpose_kernel(const float* __restrict__ W, float* __restrict__ Wt) {
    __shared__ float tile[32][33];
    int v = blockIdx.z;
    int k0 = blockIdx.x * 32, d0 = blockIdx.y * 32;
    int tx = threadIdx.x, ty = threadIdx.y;
    const float* Wv = W + (size_t)v * ND * NK;
    #pragma unroll
    for (int i = 0; i < 4; ++i)
        tile[ty + 8 * i][tx] = Wv[(size_t)(d0 + ty + 8 * i) * NK + k0 + tx];
    __syncthreads();
    float* Wtv = Wt + (size_t)v * NK * ND;
    #pragma unroll
    for (int i = 0; i < 4; ++i)
        Wtv[(size_t)(k0 + ty + 8 * i) * ND + d0 + tx] = tile[tx][ty + 8 * i];
}

__global__ __launch_bounds__(256, 4) void score_argmin(
    const float* __restrict__ X, const float* __restrict__ W,
    const double* __restrict__ wsq, int* __restrict__ idx) {
    __shared__ float Xs[TM * SX];
    __shared__ __align__(16) float Ws[DC * TC];
    const int tid = threadIdx.x;
    const int tx = tid & 15, ty = tid >> 4;
    const int v = blockIdx.x >> 6;
    const int n0 = (blockIdx.x & 63) * TM;
    const float* Xb = X + ((size_t)v * NN + n0) * ND;
    const float* Wb = W + (size_t)v * ND * NK;
    const double* wsqv = wsq + v * NK;
    double bs[8];
    int bc[8];
    #pragma unroll
    for (int i = 0; i < 8; ++i) { bs[i] = 1e300; bc[i] = 0; }
    for (int cc = 0; cc < NK / TC; ++cc) {
        float p[8][8];
        #pragma unroll
        for (int i = 0; i < 8; ++i)
            #pragma unroll
            for (int j = 0; j < 8; ++j) p[i][j] = 0.f;
        for (int dc = 0; dc < ND / DC; ++dc) {
            const int d0 = dc * DC;
            {
                const int dl2 = (tid & 15) * 2;
                const int rb = tid >> 4;
                #pragma unroll
                for (int ps = 0; ps < 8; ++ps) {
                    int r = ps * 16 + rb;
                    float2 val = *(const float2*)(Xb + (size_t)r * ND + d0 + dl2);
                    *(float2*)(&Xs[r * SX + dl2]) = val;
                }
            }
            {
                const int c4 = (tid & 31) * 4;
                const int db = tid >> 5;
                #pragma unroll
                for (int ps = 0; ps < 4; ++ps) {
                    int dl = ps * 8 + db;
                    float4 val = *(const float4*)(Wb + (size_t)(d0 + dl) * NK + cc * TC + c4);
                    *(float4*)(&Ws[dl * TC + c4]) = val;
                }
            }
            __syncthreads();
            #pragma unroll 4
            for (int dl = 0; dl < DC; ++dl) {
                float a[8];
                #pragma unroll
                for (int i = 0; i < 8; ++i) a[i] = Xs[(ty * 8 + i) * SX + dl];
                float4 b0 = *(const float4*)(&Ws[dl * TC + tx * 4]);
                float4 b1 = *(const float4*)(&Ws[dl * TC + 64 + tx * 4]);
                #pragma unroll
                for (int i = 0; i < 8; ++i) {
                    p[i][0] = fmaf(a[i], b0.x, p[i][0]);
                    p[i][1] = fmaf(a[i], b0.y, p[i][1]);
                    p[i][2] = fmaf(a[i], b0.z, p[i][2]);
                    p[i][3] = fmaf(a[i], b0.w, p[i][3]);
                    p[i][4] = fmaf(a[i], b1.x, p[i][4]);
                    p[i][5] = fmaf(a[i], b1.y, p[i][5]);
                    p[i][6] = fmaf(a[i], b1.z, p[i][6]);
                    p[i][7] = fmaf(a[i], b1.w, p[i][7]);
                }
            }
            __syncthreads();
        }
        #pragma unroll
        for (int j = 0; j < 8; ++j) {
            int cl = (j < 4) ? (tx * 4 + j) : (64 + tx * 4 + (j - 4));
            int c = cc * TC + cl;
            double w2 = wsqv[c];
            #pragma unroll
            for (int i = 0; i < 8; ++i) {
                double s = w2 - 2.0 * (double)p[i][j];
                if (s < bs[i] || (s == bs[i] && c < bc[i])) { bs[i] = s; bc[i] = c; }
            }
        }
    }
    #pragma unroll
    for (int i = 0; i < 8; ++i) {
        double s = bs[i];
        int c = bc[i];
        #pragma unroll
        for (int m = 1; m < 16; m <<= 1) {
            double s2 = __shfl_xor(s, m, 64);
            int c2 = __shfl_xor(c, m, 64);
            if (s2 < s || (s2 == s && c2 < c)) { s = s2; c = c2; }
        }
        if (tx == 0) idx[v * NN + n0 + ty * 8 + i] = c;
    }
}

// Shared by both paths.
__global__ void gather_loss(const float* __restrict__ X, const float* __restrict__ Wt,
                            const int* __restrict__ idx, float* __restrict__ out,
                            double* __restrict__ acc) {
    int tid = threadIdx.x;
    float lsum = 0.f;
    #pragma unroll
    for (int i = 0; i < 2; ++i) {
        int flat = i * 256 + tid;
        int rl = flat >> 6;
        int dpos = (flat & 63) * 4;
        size_t row = (size_t)blockIdx.x * 8 + rl;
        int k = idx[row];
        int v = (int)(row >> 13);
        float4 q = *(const float4*)(Wt + ((size_t)v * NK + k) * ND + dpos);
        float4 x = *(const float4*)(X + row * ND + dpos);
        float dx0 = q.x - x.x, dx1 = q.y - x.y, dx2 = q.z - x.z, dx3 = q.w - x.w;
        float4 o;
        o.x = x.x + dx0; o.y = x.y + dx1; o.z = x.z + dx2; o.w = x.w + dx3;
        *(float4*)(out + row * ND + dpos) = o;
        lsum += dx0 * dx0 + dx1 * dx1 + dx2 * dx2 + dx3 * dx3;
    }
    #pragma unroll
    for (int m = 32; m >= 1; m >>= 1) lsum += __shfl_down(lsum, m, 64);
    __shared__ float ws4[4];
    if ((tid & 63) == 0) ws4[tid >> 6] = lsum;
    __syncthreads();
    if (tid == 0) {
        float tot = ws4[0] + ws4[1] + ws4[2] + ws4[3];
        atomicAdd(acc, (double)tot);
    }
}

__global__ void finalize_loss(const double* __restrict__ acc, float* __restrict__ outLoss) {
    *outLoss = (float)(1.25 * (*acc) / (double)((size_t)NV * NN * ND));
}

// ===========================================================================
extern "C" void kernel_launch(void* const* d_in, const int* in_sizes, int n_in,
                              void* d_out, int out_size, void* d_ws, size_t ws_size,
                              hipStream_t stream) {
    const float* X = (const float*)d_in[0];   // [16, 8192, 256]
    const float* W = (const float*)d_in[1];   // [16, 256, 1024]
    float* out = (float*)d_out;               // [16,8192,256] + loss scalar
    char* ws = (char*)d_ws;

    // MFMA-path workspace layout
    const size_t oXh = 0;
    const size_t oXl = oXh + 67108864;
    const size_t oWht = oXl + 67108864;       // 134217728
    const size_t oWlt = oWht + 8388608;       // 142606336
    const size_t oWt = oWlt + 8388608;        // 150994944
    const size_t oWsqd = oWt + 16777216;      // 167772160
    const size_t oWsqf = oWsqd + 131072;      // 167903232
    const size_t oIdx = oWsqf + 65536;        // 167968768
    const size_t oMarg = oIdx + 524288;       // 168493056
    const size_t oList = oMarg + 524288;      // 169017344
    const size_t oAcc = oList + 524288;       // 169541632
    const size_t oCount = oAcc + 8;
    const size_t NEED = oCount + 4;           // ~161.8 MB

    if (ws_size >= NEED) {
        ushort* Xh = (ushort*)(ws + oXh);
        ushort* Xl = (ushort*)(ws + oXl);
        ushort* Wht = (ushort*)(ws + oWht);
        ushort* Wlt = (ushort*)(ws + oWlt);
        float* Wt = (float*)(ws + oWt);
        double* wsqd = (double*)(ws + oWsqd);
        float* wsqf = (float*)(ws + oWsqf);
        int* idx = (int*)(ws + oIdx);
        float* marg = (float*)(ws + oMarg);
        int* list = (int*)(ws + oList);
        double* acc = (double*)(ws + oAcc);
        int* count = (int*)(ws + oCount);

        wsq_prep<<<64, 256, 0, stream>>>(W, wsqd, wsqf, acc, count);
        prep_w<<<dim3(NK / 32, ND / 32, NV), dim3(32, 8), 0, stream>>>(W, Wt, Wht, Wlt);
        prep_x<<<2048, 256, 0, stream>>>(X, Xh, Xl);
        score_mfma<<<(NV * NN) / 128, 256, 0, stream>>>(Xh, Xl, Wht, Wlt, wsqf, idx, marg);
        compact<<<(NV * NN) / 256, 256, 0, stream>>>(marg, list, count);
        rescore<<<256, 256, 0, stream>>>(X, W, wsqd, list, count, idx);
        gather_loss<<<(NV * NN) / 8, 256, 0, stream>>>(X, Wt, idx, out, acc);
        finalize_loss<<<1, 1, 0, stream>>>(acc, out + (size_t)NV * NN * ND);
    } else {
        // Round-1 fallback (known-passing fp32 path)
        float* Wt = (float*)ws;                                    // 16 MB
        double* wsq = (double*)(ws + 16777216);                    // 128 KB
        int* idx = (int*)(ws + 16777216 + 131072);                 // 512 KB
        double* acc = (double*)(ws + 16777216 + 131072 + 524288);  // 8 B

        wsq_kernel<<<64, 256, 0, stream>>>(W, wsq, acc);
        transpose_kernel<<<dim3(NK / 32, ND / 32, NV), dim3(32, 8), 0, stream>>>(W, Wt);
        score_argmin<<<(NV * NN) / TM, 256, 0, stream>>>(X, W, wsq, idx);
        gather_loss<<<(NV * NN) / 8, 256, 0, stream>>>(X, Wt, idx, out, acc);
        finalize_loss<<<1, 1, 0, stream>>>(acc, out + (size_t)NV * NN * ND);
    }
}

// Round 3
// 714.975 us; speedup vs baseline: 2.2443x; 1.0771x over previous
//
#include <hip/hip_runtime.h>

// Problem constants (VectorQuantizer: inputs [V,N,D] fp32, embeddings [V,D,K] fp32)
#define NV 16
#define NN 8192
#define ND 256
#define NK 1024

typedef __attribute__((ext_vector_type(8))) short short8;
typedef __attribute__((ext_vector_type(4))) float f32x4;

// bf16 helpers (RNE)
__device__ __forceinline__ ushort f2bf(float f) {
    uint32_t u = __float_as_uint(f);
    uint32_t r = (u + 0x7FFFu + ((u >> 16) & 1u)) >> 16;
    return (ushort)r;
}
__device__ __forceinline__ float bf2f(ushort h) {
    return __uint_as_float(((uint32_t)h) << 16);
}

// ---------------------------------------------------------------------------
// Transpose W [V,D,K] -> Wt [V,K,D] fp32 (for gather/wsq) + bf16 limb copies.
// Wlt MUST sit exactly 4194304 ushorts after Wht (score kernel assumes it).
// ---------------------------------------------------------------------------
__global__ void prep_w(const float* __restrict__ W, float* __restrict__ Wt,
                       ushort* __restrict__ Wht, ushort* __restrict__ Wlt) {
    __shared__ float tile[32][33];
    int v = blockIdx.z;
    int k0 = blockIdx.x * 32, d0 = blockIdx.y * 32;
    int tx = threadIdx.x, ty = threadIdx.y;         // block (32,8)
    const float* Wv = W + (size_t)v * ND * NK;
    #pragma unroll
    for (int i = 0; i < 4; ++i)
        tile[ty + 8 * i][tx] = Wv[(size_t)(d0 + ty + 8 * i) * NK + k0 + tx];
    __syncthreads();
    size_t ob = (size_t)v * NK * ND;
    #pragma unroll
    for (int i = 0; i < 4; ++i) {
        float val = tile[tx][ty + 8 * i];
        size_t o = ob + (size_t)(k0 + ty + 8 * i) * ND + d0 + tx;
        Wt[o] = val;
        ushort h = f2bf(val);
        Wht[o] = h;
        Wlt[o] = f2bf(val - bf2f(h));
    }
}

// ---------------------------------------------------------------------------
// wsq from transposed Wt (coalesced): one wave per (v,k) row; double reduce.
// Also zeroes the loss/count accumulators.
// ---------------------------------------------------------------------------
__global__ void wsq_from_wt(const float* __restrict__ Wt, double* __restrict__ wsqd,
                            float* __restrict__ wsqf, double* __restrict__ acc,
                            int* __restrict__ count) {
    int row = blockIdx.x * 4 + (threadIdx.x >> 6);  // V*K rows, 4 waves/block
    int lane = threadIdx.x & 63;
    float4 wv = *(const float4*)(Wt + (size_t)row * ND + lane * 4);
    double s = (double)wv.x * wv.x + (double)wv.y * wv.y +
               (double)wv.z * wv.z + (double)wv.w * wv.w;
    #pragma unroll
    for (int m = 32; m >= 1; m >>= 1) s += __shfl_down(s, m, 64);
    if (lane == 0) { wsqd[row] = s; wsqf[row] = (float)s; }
    if (row == 0 && lane == 0) { *acc = 0.0; *count = 0; }
}

// ---------------------------------------------------------------------------
// X [V,N,D] fp32 -> Xh, Xl bf16 limb arrays (Xl = Xh + 33554432 ushorts).
// ---------------------------------------------------------------------------
__global__ void prep_x(const float* __restrict__ X, ushort* __restrict__ Xh,
                       ushort* __restrict__ Xl) {
    const int nth = gridDim.x * 256;
    for (size_t g = (size_t)blockIdx.x * 256 + threadIdx.x; g < (size_t)NV * NN * ND / 4;
         g += nth) {
        float4 x = *(const float4*)(X + g * 4);
        ushort4 h, l;
        h.x = f2bf(x.x); l.x = f2bf(x.x - bf2f(h.x));
        h.y = f2bf(x.y); l.y = f2bf(x.y - bf2f(h.y));
        h.z = f2bf(x.z); l.z = f2bf(x.z - bf2f(h.z));
        h.w = f2bf(x.w); l.w = f2bf(x.w - bf2f(h.w));
        *(ushort4*)(Xh + g * 4) = h;
        *(ushort4*)(Xl + g * 4) = l;
    }
}

// ---------------------------------------------------------------------------
// MFMA score kernel v3: 128 rows/block, TC=256 cols staged per dc (A re-read
// 4x instead of 8x), XOR-swizzled LDS quads (2-way bank access = free),
// XCD-aware block->v mapping (each XCD sees 2 codebooks -> B fits its L2).
// 2-limb bf16: dot = Xh.Wh + Xh.Wl + Xl.Wh. Tracks best + second-best.
// ---------------------------------------------------------------------------
__global__ __launch_bounds__(256, 2) void score_mfma(
    const ushort* __restrict__ Xh, const ushort* __restrict__ Wht,
    const float* __restrict__ wsqf, int* __restrict__ idx, float* __restrict__ marg) {
    // LDS: A [0,16384): limb stride 8192, slot u16 = r*4 + (q ^ ((r>>1)&3))
    //      B [16384,49152): limb stride 16384, slot u16 = c*4 + (q ^ ((c>>1)&3))
    __shared__ __align__(16) unsigned char smem[49152];

    const int tid = threadIdx.x;
    const int w = tid >> 6;
    const int l15 = tid & 15;
    const int l4 = (tid >> 4) & 3;
    // XCD swizzle: blocks dispatch round-robin over 8 XCDs by blockIdx (%8);
    // give each XCD two codebooks so B (2 x 1MB limbs) lives in its 4MB L2.
    const int b = blockIdx.x;
    const int v = (b & 7) * 2 + ((b >> 3) & 1);
    const int n0 = (b >> 4) * 128;
    const int rowq = (w & 1) * 64;                   // wave row base
    const int colq = (w >> 1) * 128;                 // wave col base in 256-chunk

    const ushort* Abase = Xh + (size_t)(v * NN + n0) * ND;     // lo limb at +33554432
    const ushort* Bbase = Wht + (size_t)v * NK * ND;           // lo limb at +4194304

    // staging source offsets (ushort units), constant per thread across (cc,dc)
    unsigned aoff[4];
    #pragma unroll
    for (int i = 0; i < 4; ++i) {
        int seg = i * 256 + tid;                     // 1024 segs of 16B
        int L = seg >> 9, r = (seg >> 2) & 127, qs = seg & 3;
        int q = qs ^ ((r >> 1) & 3);                 // swizzle: slot qs holds quad q
        aoff[i] = (unsigned)L * 33554432u + (unsigned)r * 256u + (unsigned)q * 8u;
    }
    unsigned boff[8];
    #pragma unroll
    for (int i = 0; i < 8; ++i) {
        int seg = i * 256 + tid;                     // 2048 segs of 16B
        int L = seg >> 10, c = (seg >> 2) & 255, qs = seg & 3;
        int q = qs ^ ((c >> 1) & 3);
        boff[i] = (unsigned)L * 4194304u + (unsigned)c * 256u + (unsigned)q * 8u;
    }
    // fragment read offsets (bytes), constant per thread
    unsigned aro[4], bco[8];
    #pragma unroll
    for (int rt = 0; rt < 4; ++rt) {
        int row = rowq + rt * 16 + l15;
        aro[rt] = (unsigned)(row * 4 + (l4 ^ ((row >> 1) & 3))) * 16u;
    }
    #pragma unroll
    for (int ct = 0; ct < 8; ++ct) {
        int col = colq + ct * 16 + l15;
        bco[ct] = 16384u + (unsigned)(col * 4 + (l4 ^ ((col >> 1) & 3))) * 16u;
    }

    float m1[16], m2[16];
    int c1[16];
    #pragma unroll
    for (int s = 0; s < 16; ++s) { m1[s] = 3.0e38f; m2[s] = 3.0e38f; c1[s] = 0; }

    for (int cc = 0; cc < 4; ++cc) {
        f32x4 acc[4][8];
        #pragma unroll
        for (int i = 0; i < 4; ++i)
            #pragma unroll
            for (int j = 0; j < 8; ++j) acc[i][j] = (f32x4){0.f, 0.f, 0.f, 0.f};
        const unsigned ccoff = (unsigned)cc * 65536u;           // 256 cols * ND

        for (int dc = 0; dc < 8; ++dc) {
            const unsigned d0 = dc * 32;
            #pragma unroll
            for (int i = 0; i < 4; ++i)
                __builtin_amdgcn_global_load_lds(
                    (const __attribute__((address_space(1))) void*)(Abase + aoff[i] + d0),
                    (__attribute__((address_space(3))) void*)(smem + (i * 256 + tid) * 16),
                    16, 0, 0);
            #pragma unroll
            for (int i = 0; i < 8; ++i)
                __builtin_amdgcn_global_load_lds(
                    (const __attribute__((address_space(1))) void*)(Bbase + ccoff + boff[i] + d0),
                    (__attribute__((address_space(3))) void*)(smem + 16384 + (i * 256 + tid) * 16),
                    16, 0, 0);
            __syncthreads();
            short8 Ah[4], Al[4];
            #pragma unroll
            for (int rt = 0; rt < 4; ++rt) {
                Ah[rt] = *(const short8*)(smem + aro[rt]);
                Al[rt] = *(const short8*)(smem + 8192 + aro[rt]);
            }
            #pragma unroll
            for (int ct = 0; ct < 8; ++ct) {
                short8 Bh = *(const short8*)(smem + bco[ct]);
                short8 Bl = *(const short8*)(smem + 16384 + bco[ct]);
                #pragma unroll
                for (int rt = 0; rt < 4; ++rt) {
                    acc[rt][ct] = __builtin_amdgcn_mfma_f32_16x16x32_bf16(
                        Ah[rt], Bh, acc[rt][ct], 0, 0, 0);
                    acc[rt][ct] = __builtin_amdgcn_mfma_f32_16x16x32_bf16(
                        Ah[rt], Bl, acc[rt][ct], 0, 0, 0);
                    acc[rt][ct] = __builtin_amdgcn_mfma_f32_16x16x32_bf16(
                        Al[rt], Bh, acc[rt][ct], 0, 0, 0);
                }
            }
            __syncthreads();
        }
        // fold chunk scores into running best/second (lane stream ascending c)
        #pragma unroll
        for (int ct = 0; ct < 8; ++ct) {
            int c = cc * 256 + colq + ct * 16 + l15;
            float wf = wsqf[v * NK + c];
            #pragma unroll
            for (int rt = 0; rt < 4; ++rt)
                #pragma unroll
                for (int reg = 0; reg < 4; ++reg) {
                    int slot = rt * 4 + reg;
                    float s = fmaf(-2.0f, acc[rt][ct][reg], wf);
                    bool better = s < m1[slot];
                    m2[slot] = better ? m1[slot] : fminf(m2[slot], s);
                    c1[slot] = better ? c : c1[slot];
                    m1[slot] = better ? s : m1[slot];
                }
        }
    }
    // merge across the 16 lanes sharing each row (C layout: col = lane&15)
    float* mS = (float*)smem;                        // reuse A region (post-barrier)
    int* mC = (int*)(smem + 1024);
    float* mS2 = (float*)(smem + 2048);
    #pragma unroll
    for (int rt = 0; rt < 4; ++rt)
        #pragma unroll
        for (int reg = 0; reg < 4; ++reg) {
            int slot = rt * 4 + reg;
            float s1 = m1[slot], s2v = m2[slot];
            int c = c1[slot];
            #pragma unroll
            for (int m = 1; m < 16; m <<= 1) {
                float s1o = __shfl_xor(s1, m, 64);
                float s2o = __shfl_xor(s2v, m, 64);
                int co = __shfl_xor(c, m, 64);
                bool take = (s1o < s1) || (s1o == s1 && co < c);  // tie -> smaller c
                float big = take ? s1 : s1o;
                s2v = fminf(fminf(s2v, s2o), big);
                s1 = take ? s1o : s1;
                c = take ? co : c;
            }
            if (l15 == 0) {
                int rowl = rowq + rt * 16 + l4 * 4 + reg;   // C row = quad*4+reg
                int ch = w >> 1;
                mS[ch * 128 + rowl] = s1;
                mC[ch * 128 + rowl] = c;
                mS2[ch * 128 + rowl] = s2v;
            }
        }
    __syncthreads();
    if (tid < 128) {                                  // merge the two col-halves
        float s1a = mS[tid], s1b = mS[128 + tid];
        int ca = mC[tid], cb = mC[128 + tid];
        float s2a = mS2[tid], s2b = mS2[128 + tid];
        bool take = (s1b < s1a) || (s1b == s1a && cb < ca);
        float s1 = take ? s1b : s1a;
        int c = take ? cb : ca;
        float s2v = fminf(fminf(s2a, s2b), take ? s1a : s1b);
        idx[v * NN + n0 + tid] = c;
        marg[v * NN + n0 + tid] = s2v - s1;
    }
}

// Rows with small margin -> compacted list for exact rescoring.
__global__ void compact(const float* __restrict__ marg, int* __restrict__ list,
                        int* __restrict__ count) {
    int r = blockIdx.x * 256 + threadIdx.x;
    if (marg[r] < 0.04f) {
        int p = atomicAdd(count, 1);
        list[p] = r;
    }
}

// Exact fp32 rescore (sequential fmaf over d, double compare, tie -> smaller c)
__global__ __launch_bounds__(256) void rescore(
    const float* __restrict__ X, const float* __restrict__ W,
    const double* __restrict__ wsqd, const int* __restrict__ list,
    const int* __restrict__ count, int* __restrict__ idx) {
    __shared__ float xs[256];
    __shared__ double rs[4];
    __shared__ int rc[4];
    int tid = threadIdx.x;
    int nrows = *count;
    for (int j = blockIdx.x; j < nrows; j += gridDim.x) {
        int row = list[j];
        int v = row >> 13;
        __syncthreads();
        xs[tid] = X[(size_t)row * ND + tid];
        __syncthreads();
        const float* Wv = W + (size_t)v * ND * NK;
        float p0 = 0.f, p1 = 0.f, p2 = 0.f, p3 = 0.f;
        int cb = tid * 4;
        for (int d = 0; d < ND; ++d) {
            float xd = xs[d];
            float4 wv = *(const float4*)(Wv + (size_t)d * NK + cb);
            p0 = fmaf(xd, wv.x, p0);
            p1 = fmaf(xd, wv.y, p1);
            p2 = fmaf(xd, wv.z, p2);
            p3 = fmaf(xd, wv.w, p3);
        }
        const double* wv2 = wsqd + v * NK;
        double s0 = wv2[cb] - 2.0 * (double)p0;
        double s1 = wv2[cb + 1] - 2.0 * (double)p1;
        double s2 = wv2[cb + 2] - 2.0 * (double)p2;
        double s3 = wv2[cb + 3] - 2.0 * (double)p3;
        double bsv = s0;
        int bcv = cb;
        if (s1 < bsv) { bsv = s1; bcv = cb + 1; }
        if (s2 < bsv) { bsv = s2; bcv = cb + 2; }
        if (s3 < bsv) { bsv = s3; bcv = cb + 3; }
        for (int m = 1; m < 64; m <<= 1) {
            double so = __shfl_xor(bsv, m, 64);
            int co = __shfl_xor(bcv, m, 64);
            if (so < bsv || (so == bsv && co < bcv)) { bsv = so; bcv = co; }
        }
        if ((tid & 63) == 0) { rs[tid >> 6] = bsv; rc[tid >> 6] = bcv; }
        __syncthreads();
        if (tid == 0) {
            double bq = rs[0];
            int c = rc[0];
            for (int i2 = 1; i2 < 4; ++i2)
                if (rs[i2] < bq || (rs[i2] == bq && rc[i2] < c)) { bq = rs[i2]; c = rc[i2]; }
            idx[row] = c;
        }
        __syncthreads();
    }
}

// Gather quantized rows, write output = x + (q - x), accumulate sum (q-x)^2.
__global__ void gather_loss(const float* __restrict__ X, const float* __restrict__ Wt,
                            const int* __restrict__ idx, float* __restrict__ out,
                            double* __restrict__ acc) {
    int tid = threadIdx.x;
    float lsum = 0.f;
    #pragma unroll
    for (int i = 0; i < 2; ++i) {
        int flat = i * 256 + tid;
        int rl = flat >> 6;
        int dpos = (flat & 63) * 4;
        size_t row = (size_t)blockIdx.x * 8 + rl;
        int k = idx[row];
        int v = (int)(row >> 13);
        float4 q = *(const float4*)(Wt + ((size_t)v * NK + k) * ND + dpos);
        float4 x = *(const float4*)(X + row * ND + dpos);
        float dx0 = q.x - x.x, dx1 = q.y - x.y, dx2 = q.z - x.z, dx3 = q.w - x.w;
        float4 o;
        o.x = x.x + dx0; o.y = x.y + dx1; o.z = x.z + dx2; o.w = x.w + dx3;
        *(float4*)(out + row * ND + dpos) = o;
        lsum += dx0 * dx0 + dx1 * dx1 + dx2 * dx2 + dx3 * dx3;
    }
    #pragma unroll
    for (int m = 32; m >= 1; m >>= 1) lsum += __shfl_down(lsum, m, 64);
    __shared__ float ws4[4];
    if ((tid & 63) == 0) ws4[tid >> 6] = lsum;
    __syncthreads();
    if (tid == 0) {
        float tot = ws4[0] + ws4[1] + ws4[2] + ws4[3];
        atomicAdd(acc, (double)tot);
    }
}

__global__ void finalize_loss(const double* __restrict__ acc, float* __restrict__ outLoss) {
    *outLoss = (float)(1.25 * (*acc) / (double)((size_t)NV * NN * ND));
}

// ===========================================================================
extern "C" void kernel_launch(void* const* d_in, const int* in_sizes, int n_in,
                              void* d_out, int out_size, void* d_ws, size_t ws_size,
                              hipStream_t stream) {
    const float* X = (const float*)d_in[0];   // [16, 8192, 256]
    const float* W = (const float*)d_in[1];   // [16, 256, 1024]
    float* out = (float*)d_out;               // [16,8192,256] + loss scalar
    char* ws = (char*)d_ws;

    // Workspace layout (Xl contiguous after Xh; Wlt contiguous after Wht)
    const size_t oXh = 0;
    const size_t oXl = oXh + 67108864;
    const size_t oWht = oXl + 67108864;       // 134217728
    const size_t oWlt = oWht + 8388608;       // 142606336
    const size_t oWt = oWlt + 8388608;        // 150994944
    const size_t oWsqd = oWt + 16777216;      // 167772160
    const size_t oWsqf = oWsqd + 131072;      // 167903232
    const size_t oIdx = oWsqf + 65536;        // 167968768
    const size_t oMarg = oIdx + 524288;       // 168493056
    const size_t oList = oMarg + 524288;      // 169017344
    const size_t oAcc = oList + 524288;       // 169541632
    const size_t oCount = oAcc + 8;

    ushort* Xh = (ushort*)(ws + oXh);
    ushort* Xl = (ushort*)(ws + oXl);
    ushort* Wht = (ushort*)(ws + oWht);
    ushort* Wlt = (ushort*)(ws + oWlt);
    float* Wt = (float*)(ws + oWt);
    double* wsqd = (double*)(ws + oWsqd);
    float* wsqf = (float*)(ws + oWsqf);
    int* idx = (int*)(ws + oIdx);
    float* marg = (float*)(ws + oMarg);
    int* list = (int*)(ws + oList);
    double* acc = (double*)(ws + oAcc);
    int* count = (int*)(ws + oCount);

    prep_w<<<dim3(NK / 32, ND / 32, NV), dim3(32, 8), 0, stream>>>(W, Wt, Wht, Wlt);
    wsq_from_wt<<<NV * NK / 4, 256, 0, stream>>>(Wt, wsqd, wsqf, acc, count);
    prep_x<<<2048, 256, 0, stream>>>(X, Xh, Xl);
    score_mfma<<<(NV * NN) / 128, 256, 0, stream>>>(Xh, Wht, wsqf, idx, marg);
    compact<<<(NV * NN) / 256, 256, 0, stream>>>(marg, list, count);
    rescore<<<256, 256, 0, stream>>>(X, W, wsqd, list, count, idx);
    gather_loss<<<(NV * NN) / 8, 256, 0, stream>>>(X, Wt, idx, out, acc);
    finalize_loss<<<1, 1, 0, stream>>>(acc, out + (size_t)NV * NN * ND);
}